// Round 5
// baseline (536.022 us; speedup 1.0000x reference)
//
#include <hip/hip_runtime.h>

#define NODES 50000
#define EDGES 800000
#define H 96
#define CAP 64

typedef float floatx4 __attribute__((ext_vector_type(4)));
typedef unsigned short ushort8 __attribute__((ext_vector_type(8)));
typedef __bf16 bf16x8 __attribute__((ext_vector_type(8)));

static __device__ __forceinline__ unsigned short f2b(float f) {
    unsigned int u = __float_as_uint(f);
    u = u + 0x7fffu + ((u >> 16) & 1u);   // RNE
    return (unsigned short)(u >> 16);
}
static __device__ __forceinline__ float b2f(unsigned short u) {
    return __uint_as_float(((unsigned int)u) << 16);
}
static __device__ __forceinline__ float gelu_erf(float x) {
    return 0.5f * x * (1.0f + erff(x * 0.70710678118654752f));
}
static __device__ __forceinline__ bf16x8 pack_bf8(const float* a) {
    union { ushort8 u; bf16x8 v; } r;
    #pragma unroll
    for (int j = 0; j < 8; ++j) r.u[j] = f2b(a[j]);
    return r.v;
}

// ---- Merged: GEMM1 (h = gelu(x_feat@W_pre+b)) + padded-bucket CSR scatter --
// Blocks [0, nGemmBlocks): MFMA GEMM over strips (grid-stride by wave).
// Blocks [nGemmBlocks, ...): edge scatter (independent work, hides its atomic
// latency under the GEMM's MFMA compute). count[] pre-zeroed by memset.
// mfma_f32_16x16x32_bf16: A[m=lane&15][k=quad*8+j]; B[k][n=lane&15];
// C/D col=lane&15, row=quad*4+r (m89/m91-verified).
__global__ __launch_bounds__(256) void pre_scatter(
    const float* __restrict__ A,
    const float* __restrict__ W,
    const float* __restrict__ bias,
    unsigned short* __restrict__ outp,
    const int* __restrict__ dst,
    const int* __restrict__ src,
    int* __restrict__ count,
    int2* __restrict__ csr,
    int nStrips, int nGemmBlocks)
{
    __shared__ unsigned short Wt[96][104];  // [n][k] bf16
    const int tid = threadIdx.x;

    if (blockIdx.x >= nGemmBlocks) {        // ---- scatter blocks
        const int e = (blockIdx.x - nGemmBlocks) * 256 + tid;
        if (e < EDGES) {
            const int d = dst[e];
            const int c = atomicAdd(&count[d], 1);
            if (c < CAP) {                   // overflow guard (P~0 at deg~16)
                int2 es; es.x = e; es.y = src[e];
                csr[d * CAP + c] = es;
            }
        }
        return;
    }

    // ---- GEMM blocks
    #pragma unroll
    for (int j = 0; j < 36; ++j) {          // 9216 = 256*36
        const int f = tid + 256 * j;
        const int k = f / 96, n = f - k * 96;
        Wt[n][k] = f2b(W[f]);
    }
    __syncthreads();

    const int lane = tid & 63;
    const int quad = lane >> 4;
    const int l16  = lane & 15;

    bf16x8 Bf[3][6];
    float  bv[6];
    #pragma unroll
    for (int ks = 0; ks < 3; ++ks)
        #pragma unroll
        for (int nt = 0; nt < 6; ++nt)
            Bf[ks][nt] = *(const bf16x8*)(&Wt[nt * 16 + l16][ks * 32 + quad * 8]);
    #pragma unroll
    for (int nt = 0; nt < 6; ++nt) bv[nt] = bias[nt * 16 + l16];

    const int gwave  = (blockIdx.x * 256 + tid) >> 6;
    const int nWaves = (nGemmBlocks * 256) >> 6;

    for (int strip = gwave; strip < nStrips; strip += nWaves) {
        const int row0 = strip * 16;
        const float* Ap = A + (size_t)(row0 + l16) * H + quad * 8;

        bf16x8 Af[3];
        #pragma unroll
        for (int ks = 0; ks < 3; ++ks) {
            float tmp[8];
            const floatx4 a0 = *(const floatx4*)(Ap + ks * 32);
            const floatx4 a1 = *(const floatx4*)(Ap + ks * 32 + 4);
            #pragma unroll
            for (int j = 0; j < 4; ++j) { tmp[j] = a0[j]; tmp[4 + j] = a1[j]; }
            Af[ks] = pack_bf8(tmp);
        }

        floatx4 acc[6];
        #pragma unroll
        for (int nt = 0; nt < 6; ++nt) acc[nt] = (floatx4){0.f, 0.f, 0.f, 0.f};
        #pragma unroll
        for (int ks = 0; ks < 3; ++ks)
            #pragma unroll
            for (int nt = 0; nt < 6; ++nt)
                acc[nt] = __builtin_amdgcn_mfma_f32_16x16x32_bf16(Af[ks], Bf[ks][nt], acc[nt], 0, 0, 0);

        #pragma unroll
        for (int nt = 0; nt < 6; ++nt) {
            const int col = nt * 16 + l16;
            #pragma unroll
            for (int r = 0; r < 4; ++r) {
                const int row = row0 + quad * 4 + r;
                outp[(size_t)row * H + col] = f2b(gelu_erf(acc[nt][r] + bv[nt]));
            }
        }
    }
}

// ---------------- Pull-aggregate + residual: xb = x_feat + sum --------------
// Latency-bound => maximize TLP: zero LDS, VGPR<=64 (8 waves/SIMD),
// 12 threads/node x 8 feats, edge loop unrolled x2 for MLP.
// Read-once streams (csr, bases, x_feat) use NON-TEMPORAL loads so the 307 MB
// bases stream doesn't evict the 9.6 MB h table from L2/L3.
__global__ __launch_bounds__(256, 8) void gather_nodes(
    const unsigned short* __restrict__ h,
    const float* __restrict__ bases,
    const int2* __restrict__ csr,
    const int* __restrict__ count,
    const float* __restrict__ x_feat,
    float* __restrict__ xb)
{
    const int t = blockIdx.x * 256 + threadIdx.x;
    const int n = t / 12;
    if (n >= NODES) return;
    const int seg = t - n * 12;
    const int so8 = seg * 8;
    const int i0 = n * CAP;
    const int i1 = i0 + min(count[n], CAP);

    floatx4 acc0 = (floatx4){0.f, 0.f, 0.f, 0.f};
    floatx4 acc1 = (floatx4){0.f, 0.f, 0.f, 0.f};

    int i = i0;
    for (; i + 1 < i1; i += 2) {          // 2 independent edges in flight
        const unsigned long long pa =
            __builtin_nontemporal_load((const unsigned long long*)&csr[i]);
        const unsigned long long pb =
            __builtin_nontemporal_load((const unsigned long long*)&csr[i + 1]);
        const int ea = (int)pa, sa = (int)(pa >> 32);
        const int eb = (int)pb, sb = (int)(pb >> 32);
        const float* bpa = bases + (size_t)ea * H + so8;
        const float* bpb = bases + (size_t)eb * H + so8;
        const floatx4 ba0 = __builtin_nontemporal_load((const floatx4*)(bpa));
        const floatx4 ba1 = __builtin_nontemporal_load((const floatx4*)(bpa + 4));
        const ushort8 hva = *(const ushort8*)(h + (size_t)sa * H + so8);
        const floatx4 bb0 = __builtin_nontemporal_load((const floatx4*)(bpb));
        const floatx4 bb1 = __builtin_nontemporal_load((const floatx4*)(bpb + 4));
        const ushort8 hvb = *(const ushort8*)(h + (size_t)sb * H + so8);
        #pragma unroll
        for (int j = 0; j < 4; ++j) {
            acc0[j] = fmaf(ba0[j], b2f(hva[j]),     acc0[j]);
            acc1[j] = fmaf(ba1[j], b2f(hva[4 + j]), acc1[j]);
        }
        #pragma unroll
        for (int j = 0; j < 4; ++j) {
            acc0[j] = fmaf(bb0[j], b2f(hvb[j]),     acc0[j]);
            acc1[j] = fmaf(bb1[j], b2f(hvb[4 + j]), acc1[j]);
        }
    }
    if (i < i1) {                          // odd remainder
        const unsigned long long pa =
            __builtin_nontemporal_load((const unsigned long long*)&csr[i]);
        const int ea = (int)pa, sa = (int)(pa >> 32);
        const float* bpa = bases + (size_t)ea * H + so8;
        const floatx4 ba0 = __builtin_nontemporal_load((const floatx4*)(bpa));
        const floatx4 ba1 = __builtin_nontemporal_load((const floatx4*)(bpa + 4));
        const ushort8 hva = *(const ushort8*)(h + (size_t)sa * H + so8);
        #pragma unroll
        for (int j = 0; j < 4; ++j) {
            acc0[j] = fmaf(ba0[j], b2f(hva[j]),     acc0[j]);
            acc1[j] = fmaf(ba1[j], b2f(hva[4 + j]), acc1[j]);
        }
    }

    const size_t no = (size_t)n * H + so8;
    const floatx4 x0 = __builtin_nontemporal_load((const floatx4*)(x_feat + no));
    const floatx4 x1 = __builtin_nontemporal_load((const floatx4*)(x_feat + no + 4));
    #pragma unroll
    for (int j = 0; j < 4; ++j) { acc0[j] += x0[j]; acc1[j] += x1[j]; }
    *(floatx4*)(xb + no)     = acc0;
    *(floatx4*)(xb + no + 4) = acc1;
}

// ---------------- Fused FFN: out = xb + gelu(gelu(xb@W1+b1)@W2+b2) ----------
// A read fp32 + in-reg bf16 cvt; t redistributed C->A layout through a
// per-wave XOR-swizzled LDS scratch (same-wave in-order DS, no barriers).
__global__ __launch_bounds__(256) void ffn_dual(
    const float* __restrict__ A,        // xb fp32 [N][96]
    const float* __restrict__ W1, const float* __restrict__ b1,
    const float* __restrict__ W2, const float* __restrict__ b2,
    float* __restrict__ outp,
    int nStrips)
{
    __shared__ unsigned short Wt1[96][104];   // [n][k] bf16
    __shared__ unsigned short Wt2[96][104];
    __shared__ unsigned short St[4][16][112]; // per-wave t scratch (swizzled)

    const int tid = threadIdx.x;
    #pragma unroll
    for (int j = 0; j < 36; ++j) {
        const int f = tid + 256 * j;
        const int k = f / 96, n = f - k * 96;
        Wt1[n][k] = f2b(W1[f]);
        Wt2[n][k] = f2b(W2[f]);
    }
    __syncthreads();

    const int lane = tid & 63;
    const int quad = lane >> 4;
    const int l16  = lane & 15;
    const int w    = tid >> 6;

    float bv1[6], bv2[6];
    #pragma unroll
    for (int nt = 0; nt < 6; ++nt) {
        bv1[nt] = b1[nt * 16 + l16];
        bv2[nt] = b2[nt * 16 + l16];
    }

    const int wsw = quad << 3;                // write swizzle (validated R3/R4)
    const int rsw = (l16 >> 2) << 3;          // read swizzle

    const int gwave  = (blockIdx.x * 256 + tid) >> 6;
    const int nWaves = (gridDim.x * 256) >> 6;

    for (int strip = gwave; strip < nStrips; strip += nWaves) {
        const int row0 = strip * 16;
        const float* Ap = A + (size_t)(row0 + l16) * H + quad * 8;

        // ---- stage 1: t = gelu(xb @ W1 + b1)
        bf16x8 Af[3];
        #pragma unroll
        for (int ks = 0; ks < 3; ++ks) {
            float tmp[8];
            const floatx4 a0 = *(const floatx4*)(Ap + ks * 32);
            const floatx4 a1 = *(const floatx4*)(Ap + ks * 32 + 4);
            #pragma unroll
            for (int j = 0; j < 4; ++j) { tmp[j] = a0[j]; tmp[4 + j] = a1[j]; }
            Af[ks] = pack_bf8(tmp);
        }
        floatx4 facc[6];
        #pragma unroll
        for (int nt = 0; nt < 6; ++nt) facc[nt] = (floatx4){0.f, 0.f, 0.f, 0.f};
        #pragma unroll
        for (int ks = 0; ks < 3; ++ks)
            #pragma unroll
            for (int nt = 0; nt < 6; ++nt) {
                const bf16x8 Bf1 = *(const bf16x8*)(&Wt1[nt * 16 + l16][ks * 32 + quad * 8]);
                facc[nt] = __builtin_amdgcn_mfma_f32_16x16x32_bf16(Af[ks], Bf1, facc[nt], 0, 0, 0);
            }

        // ---- t C-layout -> A-layout via per-wave swizzled scratch
        #pragma unroll
        for (int nt = 0; nt < 6; ++nt)
            #pragma unroll
            for (int r = 0; r < 4; ++r)
                St[w][quad * 4 + r][(nt * 16 + l16) ^ wsw] =
                    f2b(gelu_erf(facc[nt][r] + bv1[nt]));
        bf16x8 Tf[3];
        #pragma unroll
        for (int ks = 0; ks < 3; ++ks)
            Tf[ks] = *(const bf16x8*)(&St[w][l16][(ks * 32 + quad * 8) ^ rsw]);

        // ---- stage 2: out = xb + gelu(t @ W2 + b2)
        #pragma unroll
        for (int nt = 0; nt < 6; ++nt) facc[nt] = (floatx4){0.f, 0.f, 0.f, 0.f};
        #pragma unroll
        for (int ks = 0; ks < 3; ++ks)
            #pragma unroll
            for (int nt = 0; nt < 6; ++nt) {
                const bf16x8 Bf2 = *(const bf16x8*)(&Wt2[nt * 16 + l16][ks * 32 + quad * 8]);
                facc[nt] = __builtin_amdgcn_mfma_f32_16x16x32_bf16(Tf[ks], Bf2, facc[nt], 0, 0, 0);
            }
        #pragma unroll
        for (int nt = 0; nt < 6; ++nt) {
            const int col = nt * 16 + l16;
            #pragma unroll
            for (int r = 0; r < 4; ++r) {
                const int row = row0 + quad * 4 + r;
                const size_t o = (size_t)row * H + col;
                outp[o] = A[o] + gelu_erf(facc[nt][r] + bv2[nt]);
            }
        }
    }
}

extern "C" void kernel_launch(void* const* d_in, const int* in_sizes, int n_in,
                              void* d_out, int out_size, void* d_ws, size_t ws_size,
                              hipStream_t stream)
{
    const float* x_feat = (const float*)d_in[0];
    const float* bases  = (const float*)d_in[1];
    const float* W_pre  = (const float*)d_in[2];
    const float* b_pre  = (const float*)d_in[3];
    const float* W1     = (const float*)d_in[4];
    const float* b1     = (const float*)d_in[5];
    const float* W2     = (const float*)d_in[6];
    const float* b2     = (const float*)d_in[7];
    const int* src = (const int*)d_in[8];
    const int* dst = (const int*)d_in[9];

    char* ws = (char*)d_ws;
    int*            count  = (int*)(ws);                       // 200,000 B
    int2*           csr2   = (int2*)(ws + 1048576);            // 25,600,000 B
    unsigned short* h_bf   = (unsigned short*)(ws + 27262976); // 9,600,000 B
    float*          xb     = (float*)(ws + 37748736);          // 19,200,000 B
    float*          out    = (float*)d_out;

    const int nStrips     = NODES / 16;                        // 3125 exact
    const int nGemmBlocks = 512;
    const int nScatBlocks = (EDGES + 255) / 256;               // 3125

    hipMemsetAsync(count, 0, NODES * sizeof(int), stream);
    // h = gelu(x_feat @ W_pre + b_pre) -> bf16, concurrent with CSR scatter
    pre_scatter<<<nGemmBlocks + nScatBlocks, 256, 0, stream>>>(
        x_feat, W_pre, b_pre, h_bf, dst, src, count, csr2, nStrips, nGemmBlocks);
    // xb = x_feat + pull-sum(h[src]*bases)  -- full-occupancy latency hiding
    gather_nodes<<<(NODES * 12 + 255) / 256, 256, 0, stream>>>(
        h_bf, bases, csr2, count, x_feat, xb);
    // out = xb + gelu(gelu(xb@W1+b1)@W2+b2)
    ffn_dual<<<512, 256, 0, stream>>>(xb, W1, b1, W2, b2, out, nStrips);
}

// Round 6
// 519.125 us; speedup vs baseline: 1.0325x; 1.0325x over previous
//
#include <hip/hip_runtime.h>

#define NODES 50000
#define EDGES 800000
#define H 96
#define CAP 64

typedef float floatx4 __attribute__((ext_vector_type(4)));
typedef unsigned short ushort8 __attribute__((ext_vector_type(8)));
typedef __bf16 bf16x8 __attribute__((ext_vector_type(8)));

static __device__ __forceinline__ unsigned short f2b(float f) {
    unsigned int u = __float_as_uint(f);
    u = u + 0x7fffu + ((u >> 16) & 1u);   // RNE
    return (unsigned short)(u >> 16);
}
static __device__ __forceinline__ float b2f(unsigned short u) {
    return __uint_as_float(((unsigned int)u) << 16);
}
static __device__ __forceinline__ float gelu_erf(float x) {
    return 0.5f * x * (1.0f + erff(x * 0.70710678118654752f));
}
static __device__ __forceinline__ bf16x8 pack_bf8(const float* a) {
    union { ushort8 u; bf16x8 v; } r;
    #pragma unroll
    for (int j = 0; j < 8; ++j) r.u[j] = f2b(a[j]);
    return r.v;
}

// ---- Merged: GEMM1 (h = gelu(x_feat@W_pre+b)) + padded-bucket CSR scatter --
// Blocks [0, nGemmBlocks): MFMA GEMM over strips (grid-stride by wave).
// Blocks [nGemmBlocks, ...): edge scatter, 4 edges/thread (int4 loads, 4
// independent atomics in flight). count[] pre-zeroed by memset.
// mfma_f32_16x16x32_bf16: A[m=lane&15][k=quad*8+j]; B[k][n=lane&15];
// C/D col=lane&15, row=quad*4+r (m89/m91-verified).
__global__ __launch_bounds__(256) void pre_scatter(
    const float* __restrict__ A,
    const float* __restrict__ W,
    const float* __restrict__ bias,
    unsigned short* __restrict__ outp,
    const int* __restrict__ dst,
    const int* __restrict__ src,
    int* __restrict__ count,
    int2* __restrict__ csr,
    int nStrips, int nGemmBlocks)
{
    __shared__ unsigned short Wt[96][104];  // [n][k] bf16
    const int tid = threadIdx.x;

    if (blockIdx.x >= nGemmBlocks) {        // ---- scatter blocks, 4 edges/thread
        const int base = ((blockIdx.x - nGemmBlocks) * 256 + tid) * 4;
        if (base + 3 < EDGES) {
            const int4 d4 = *(const int4*)(dst + base);
            const int4 s4 = *(const int4*)(src + base);
            const int dd[4] = {d4.x, d4.y, d4.z, d4.w};
            const int ss[4] = {s4.x, s4.y, s4.z, s4.w};
            int cc[4];
            #pragma unroll
            for (int j = 0; j < 4; ++j) cc[j] = atomicAdd(&count[dd[j]], 1);
            #pragma unroll
            for (int j = 0; j < 4; ++j) {
                if (cc[j] < CAP) {           // overflow guard (P~0 at deg~16)
                    int2 es; es.x = base + j; es.y = ss[j];
                    csr[dd[j] * CAP + cc[j]] = es;
                }
            }
        } else if (base < EDGES) {
            #pragma unroll
            for (int j = 0; j < 4; ++j) {
                const int e = base + j;
                if (e < EDGES) {
                    const int d = dst[e];
                    const int c = atomicAdd(&count[d], 1);
                    if (c < CAP) {
                        int2 es; es.x = e; es.y = src[e];
                        csr[d * CAP + c] = es;
                    }
                }
            }
        }
        return;
    }

    // ---- GEMM blocks
    #pragma unroll
    for (int j = 0; j < 36; ++j) {          // 9216 = 256*36
        const int f = tid + 256 * j;
        const int k = f / 96, n = f - k * 96;
        Wt[n][k] = f2b(W[f]);
    }
    __syncthreads();

    const int lane = tid & 63;
    const int quad = lane >> 4;
    const int l16  = lane & 15;

    bf16x8 Bf[3][6];
    float  bv[6];
    #pragma unroll
    for (int ks = 0; ks < 3; ++ks)
        #pragma unroll
        for (int nt = 0; nt < 6; ++nt)
            Bf[ks][nt] = *(const bf16x8*)(&Wt[nt * 16 + l16][ks * 32 + quad * 8]);
    #pragma unroll
    for (int nt = 0; nt < 6; ++nt) bv[nt] = bias[nt * 16 + l16];

    const int gwave  = (blockIdx.x * 256 + tid) >> 6;
    const int nWaves = (nGemmBlocks * 256) >> 6;

    for (int strip = gwave; strip < nStrips; strip += nWaves) {
        const int row0 = strip * 16;
        const float* Ap = A + (size_t)(row0 + l16) * H + quad * 8;

        bf16x8 Af[3];
        #pragma unroll
        for (int ks = 0; ks < 3; ++ks) {
            float tmp[8];
            const floatx4 a0 = *(const floatx4*)(Ap + ks * 32);
            const floatx4 a1 = *(const floatx4*)(Ap + ks * 32 + 4);
            #pragma unroll
            for (int j = 0; j < 4; ++j) { tmp[j] = a0[j]; tmp[4 + j] = a1[j]; }
            Af[ks] = pack_bf8(tmp);
        }

        floatx4 acc[6];
        #pragma unroll
        for (int nt = 0; nt < 6; ++nt) acc[nt] = (floatx4){0.f, 0.f, 0.f, 0.f};
        #pragma unroll
        for (int ks = 0; ks < 3; ++ks)
            #pragma unroll
            for (int nt = 0; nt < 6; ++nt)
                acc[nt] = __builtin_amdgcn_mfma_f32_16x16x32_bf16(Af[ks], Bf[ks][nt], acc[nt], 0, 0, 0);

        #pragma unroll
        for (int nt = 0; nt < 6; ++nt) {
            const int col = nt * 16 + l16;
            #pragma unroll
            for (int r = 0; r < 4; ++r) {
                const int row = row0 + quad * 4 + r;
                outp[(size_t)row * H + col] = f2b(gelu_erf(acc[nt][r] + bv[nt]));
            }
        }
    }
}

// ---------------- Pull-aggregate + residual: xb = x_feat + sum --------------
// Latency-bound => MLP x occupancy tradeoff: launch_bounds(256,6) gives an
// 84-VGPR budget so the unroll-2 body's 6 loads genuinely coexist in flight
// (at 64 VGPR the scheduler serializes the two edges). 12 threads/node.
// NT loads only on true read-once streams (bases, x_feat); csr keeps L1
// broadcast reuse across the 12 lanes sharing each entry.
__global__ __launch_bounds__(256, 6) void gather_nodes(
    const unsigned short* __restrict__ h,
    const float* __restrict__ bases,
    const int2* __restrict__ csr,
    const int* __restrict__ count,
    const float* __restrict__ x_feat,
    float* __restrict__ xb)
{
    const int t = blockIdx.x * 256 + threadIdx.x;
    const int n = t / 12;
    if (n >= NODES) return;
    const int seg = t - n * 12;
    const int so8 = seg * 8;
    const int i0 = n * CAP;
    const int i1 = i0 + min(count[n], CAP);

    floatx4 acc0 = (floatx4){0.f, 0.f, 0.f, 0.f};
    floatx4 acc1 = (floatx4){0.f, 0.f, 0.f, 0.f};

    int i = i0;
    for (; i + 1 < i1; i += 2) {          // 2 independent edges in flight
        const int2 ea = csr[i];
        const int2 eb = csr[i + 1];
        const float* bpa = bases + (size_t)ea.x * H + so8;
        const float* bpb = bases + (size_t)eb.x * H + so8;
        const floatx4 ba0 = __builtin_nontemporal_load((const floatx4*)(bpa));
        const floatx4 ba1 = __builtin_nontemporal_load((const floatx4*)(bpa + 4));
        const ushort8 hva = *(const ushort8*)(h + (size_t)ea.y * H + so8);
        const floatx4 bb0 = __builtin_nontemporal_load((const floatx4*)(bpb));
        const floatx4 bb1 = __builtin_nontemporal_load((const floatx4*)(bpb + 4));
        const ushort8 hvb = *(const ushort8*)(h + (size_t)eb.y * H + so8);
        #pragma unroll
        for (int j = 0; j < 4; ++j) {
            acc0[j] = fmaf(ba0[j], b2f(hva[j]),     acc0[j]);
            acc1[j] = fmaf(ba1[j], b2f(hva[4 + j]), acc1[j]);
        }
        #pragma unroll
        for (int j = 0; j < 4; ++j) {
            acc0[j] = fmaf(bb0[j], b2f(hvb[j]),     acc0[j]);
            acc1[j] = fmaf(bb1[j], b2f(hvb[4 + j]), acc1[j]);
        }
    }
    if (i < i1) {                          // odd remainder
        const int2 ea = csr[i];
        const float* bpa = bases + (size_t)ea.x * H + so8;
        const floatx4 ba0 = __builtin_nontemporal_load((const floatx4*)(bpa));
        const floatx4 ba1 = __builtin_nontemporal_load((const floatx4*)(bpa + 4));
        const ushort8 hva = *(const ushort8*)(h + (size_t)ea.y * H + so8);
        #pragma unroll
        for (int j = 0; j < 4; ++j) {
            acc0[j] = fmaf(ba0[j], b2f(hva[j]),     acc0[j]);
            acc1[j] = fmaf(ba1[j], b2f(hva[4 + j]), acc1[j]);
        }
    }

    const size_t no = (size_t)n * H + so8;
    const floatx4 x0 = __builtin_nontemporal_load((const floatx4*)(x_feat + no));
    const floatx4 x1 = __builtin_nontemporal_load((const floatx4*)(x_feat + no + 4));
    #pragma unroll
    for (int j = 0; j < 4; ++j) { acc0[j] += x0[j]; acc1[j] += x1[j]; }
    *(floatx4*)(xb + no)     = acc0;
    *(floatx4*)(xb + no + 4) = acc1;
}

// ---------------- Fused FFN: out = xb + gelu(gelu(xb@W1+b1)@W2+b2) ----------
// A read fp32 + in-reg bf16 cvt; t redistributed C->A layout through a
// per-wave XOR-swizzled LDS scratch (same-wave in-order DS, no barriers).
__global__ __launch_bounds__(256) void ffn_dual(
    const float* __restrict__ A,        // xb fp32 [N][96]
    const float* __restrict__ W1, const float* __restrict__ b1,
    const float* __restrict__ W2, const float* __restrict__ b2,
    float* __restrict__ outp,
    int nStrips)
{
    __shared__ unsigned short Wt1[96][104];   // [n][k] bf16
    __shared__ unsigned short Wt2[96][104];
    __shared__ unsigned short St[4][16][112]; // per-wave t scratch (swizzled)

    const int tid = threadIdx.x;
    #pragma unroll
    for (int j = 0; j < 36; ++j) {
        const int f = tid + 256 * j;
        const int k = f / 96, n = f - k * 96;
        Wt1[n][k] = f2b(W1[f]);
        Wt2[n][k] = f2b(W2[f]);
    }
    __syncthreads();

    const int lane = tid & 63;
    const int quad = lane >> 4;
    const int l16  = lane & 15;
    const int w    = tid >> 6;

    float bv1[6], bv2[6];
    #pragma unroll
    for (int nt = 0; nt < 6; ++nt) {
        bv1[nt] = b1[nt * 16 + l16];
        bv2[nt] = b2[nt * 16 + l16];
    }

    const int wsw = quad << 3;                // write swizzle (validated R3-R5)
    const int rsw = (l16 >> 2) << 3;          // read swizzle

    const int gwave  = (blockIdx.x * 256 + tid) >> 6;
    const int nWaves = (gridDim.x * 256) >> 6;

    for (int strip = gwave; strip < nStrips; strip += nWaves) {
        const int row0 = strip * 16;
        const float* Ap = A + (size_t)(row0 + l16) * H + quad * 8;

        // ---- stage 1: t = gelu(xb @ W1 + b1)
        bf16x8 Af[3];
        #pragma unroll
        for (int ks = 0; ks < 3; ++ks) {
            float tmp[8];
            const floatx4 a0 = *(const floatx4*)(Ap + ks * 32);
            const floatx4 a1 = *(const floatx4*)(Ap + ks * 32 + 4);
            #pragma unroll
            for (int j = 0; j < 4; ++j) { tmp[j] = a0[j]; tmp[4 + j] = a1[j]; }
            Af[ks] = pack_bf8(tmp);
        }
        floatx4 facc[6];
        #pragma unroll
        for (int nt = 0; nt < 6; ++nt) facc[nt] = (floatx4){0.f, 0.f, 0.f, 0.f};
        #pragma unroll
        for (int ks = 0; ks < 3; ++ks)
            #pragma unroll
            for (int nt = 0; nt < 6; ++nt) {
                const bf16x8 Bf1 = *(const bf16x8*)(&Wt1[nt * 16 + l16][ks * 32 + quad * 8]);
                facc[nt] = __builtin_amdgcn_mfma_f32_16x16x32_bf16(Af[ks], Bf1, facc[nt], 0, 0, 0);
            }

        // ---- t C-layout -> A-layout via per-wave swizzled scratch
        #pragma unroll
        for (int nt = 0; nt < 6; ++nt)
            #pragma unroll
            for (int r = 0; r < 4; ++r)
                St[w][quad * 4 + r][(nt * 16 + l16) ^ wsw] =
                    f2b(gelu_erf(facc[nt][r] + bv1[nt]));
        bf16x8 Tf[3];
        #pragma unroll
        for (int ks = 0; ks < 3; ++ks)
            Tf[ks] = *(const bf16x8*)(&St[w][l16][(ks * 32 + quad * 8) ^ rsw]);

        // ---- stage 2: out = xb + gelu(t @ W2 + b2)
        #pragma unroll
        for (int nt = 0; nt < 6; ++nt) facc[nt] = (floatx4){0.f, 0.f, 0.f, 0.f};
        #pragma unroll
        for (int ks = 0; ks < 3; ++ks)
            #pragma unroll
            for (int nt = 0; nt < 6; ++nt) {
                const bf16x8 Bf2 = *(const bf16x8*)(&Wt2[nt * 16 + l16][ks * 32 + quad * 8]);
                facc[nt] = __builtin_amdgcn_mfma_f32_16x16x32_bf16(Tf[ks], Bf2, facc[nt], 0, 0, 0);
            }
        #pragma unroll
        for (int nt = 0; nt < 6; ++nt) {
            const int col = nt * 16 + l16;
            #pragma unroll
            for (int r = 0; r < 4; ++r) {
                const int row = row0 + quad * 4 + r;
                const size_t o = (size_t)row * H + col;
                outp[o] = A[o] + gelu_erf(facc[nt][r] + bv2[nt]);
            }
        }
    }
}

extern "C" void kernel_launch(void* const* d_in, const int* in_sizes, int n_in,
                              void* d_out, int out_size, void* d_ws, size_t ws_size,
                              hipStream_t stream)
{
    const float* x_feat = (const float*)d_in[0];
    const float* bases  = (const float*)d_in[1];
    const float* W_pre  = (const float*)d_in[2];
    const float* b_pre  = (const float*)d_in[3];
    const float* W1     = (const float*)d_in[4];
    const float* b1     = (const float*)d_in[5];
    const float* W2     = (const float*)d_in[6];
    const float* b2     = (const float*)d_in[7];
    const int* src = (const int*)d_in[8];
    const int* dst = (const int*)d_in[9];

    char* ws = (char*)d_ws;
    int*            count  = (int*)(ws);                       // 200,000 B
    int2*           csr2   = (int2*)(ws + 1048576);            // 25,600,000 B
    unsigned short* h_bf   = (unsigned short*)(ws + 27262976); // 9,600,000 B
    float*          xb     = (float*)(ws + 37748736);          // 19,200,000 B
    float*          out    = (float*)d_out;

    const int nStrips     = NODES / 16;                        // 3125 exact
    const int nGemmBlocks = 512;
    const int nScatBlocks = (EDGES + 1023) / 1024;             // 782 (4 edges/thread)

    hipMemsetAsync(count, 0, NODES * sizeof(int), stream);
    // h = gelu(x_feat @ W_pre + b_pre) -> bf16, concurrent with CSR scatter
    pre_scatter<<<nGemmBlocks + nScatBlocks, 256, 0, stream>>>(
        x_feat, W_pre, b_pre, h_bf, dst, src, count, csr2, nStrips, nGemmBlocks);
    // xb = x_feat + pull-sum(h[src]*bases)
    gather_nodes<<<(NODES * 12 + 255) / 256, 256, 0, stream>>>(
        h_bf, bases, csr2, count, x_feat, xb);
    // out = xb + gelu(gelu(xb@W1+b1)@W2+b2)
    ffn_dual<<<512, 256, 0, stream>>>(xb, W1, b1, W2, b2, out, nStrips);
}